// Round 6
// baseline (3638.798 us; speedup 1.0000x reference)
//
#include <hip/hip_runtime.h>

// Fused per-batch graph encoder, v6: MFMA bf16 + packed weights + scalarized
// accumulator state (no ext_vector arrays -> no alloca -> no scratch).
// 512 threads (8 waves)/block, 48KB LDS. Each wave owns 1-2 16-row output
// tiles end-to-end: MFMA acc in named regs -> 16-lane shfl LN -> bf16
// writeback. B-fragments pre-packed in d_ws (1KB blocks, L2-hot).

#define BLK 512

typedef short v4s __attribute__((ext_vector_type(4)));
typedef short v8s __attribute__((ext_vector_type(8)));
typedef float v4f __attribute__((ext_vector_type(4)));

// byte offsets into the 49152-B shared block
#define ACTS    0              // 160 rows x 64 col bf16, stride 128, swz mask 15
#define GATA    20480          // 145 rows x 64 (h_from_v / v_from_h / e_from_v)
#define GATB    40960          // 54 rows x 64 (v_from_e)
// stage-0 overlays (GATA/GATB free until the rounds)
#define S0TILEF (GATA + 0)     // 19x32 f32, plain
#define S0VRAWF (GATA + 2432)  // 54x32 f32, plain
#define S0TILEB (GATA + 9344)  // 32x32 bf16, stride 64, swz mask 7
#define S0VRAWB (GATA + 11392) // 64x32 bf16
#define S0ERAWB (GATB + 0)     // 72x32 bf16
// post-round overlays (gathers dead by then)
#define POOLF   (GATB + 6144)  // 192 f32
#define RACC    (GATB + 6912)  // 64 f32

// packed-W frag-block bases (1 block = 64 lanes x 8 bf16 = 1KB)
#define FB_HIN 0
#define FB_VIN 4
#define FB_EIN 8
#define FB_HU  12   // +16 per round
#define FB_VU  44   // +24 per round
#define FB_EU  92   // +16 per round
#define NFB    124

struct Acc4 { v4f c0, c1, c2, c3; };

__device__ __forceinline__ unsigned short f2bf(float f){
  unsigned u = __float_as_uint(f);
  return (unsigned short)((u + 0x7fffu + ((u >> 16) & 1u)) >> 16);
}
__device__ __forceinline__ float bf2f(unsigned short h){
  return __uint_as_float(((unsigned)h) << 16);
}

__device__ __forceinline__ float red16(float v){
  v += __shfl_xor(v, 1, 64);
  v += __shfl_xor(v, 2, 64);
  v += __shfl_xor(v, 4, 64);
  v += __shfl_xor(v, 8, 64);
  return v;
}
__device__ __forceinline__ float red64(float v){
#pragma unroll
  for (int m = 32; m >= 1; m >>= 1) v += __shfl_xor(v, m, 64);
  return v;
}

__device__ __forceinline__ int swz_off(int base, int stride, int row, int col, int m){
  return base + row*stride + ((((col >> 2) ^ (row & m)) << 3) + ((col & 3) << 1));
}
__device__ __forceinline__ unsigned short lds_bf_read(const unsigned char* sm, int base, int stride, int row, int col, int m){
  return *(const unsigned short*)(sm + swz_off(base, stride, row, col, m));
}
__device__ __forceinline__ void lds_bf_write(unsigned char* sm, int base, int stride, int row, int col, int m, unsigned short v){
  *(unsigned short*)(sm + swz_off(base, stride, row, col, m)) = v;
}

// A-fragment: lane l row=(l&15), k(j) = 32*seg + 16*(j>>2) + 4*(l>>4) + (j&3).
__device__ __forceinline__ v8s load_frag(const unsigned char* sm, int base, int stride, int row, int cb, int m){
  v4s lo = *(const v4s*)(sm + base + row*stride + (((cb    ) ^ (row & m)) << 3));
  v4s hi = *(const v4s*)(sm + base + row*stride + (((cb + 4) ^ (row & m)) << 3));
  v8s r; r[0]=lo[0]; r[1]=lo[1]; r[2]=lo[2]; r[3]=lo[3]; r[4]=hi[0]; r[5]=hi[1]; r[6]=hi[2]; r[7]=hi[3];
  return r;
}

// TYPE: 0=hex 1=vtx 2=edge. S0: stage-0 (K=32). wp = packed frag base.
template<int TYPE, bool S0>
__device__ __forceinline__ void tile_accum(const unsigned char* sm, int roff, int lane,
                                           const v8s* __restrict__ wp, Acc4& A)
{
  constexpr int NSEG = S0 ? 1 : (TYPE == 1 ? 6 : 4);
  constexpr int STR  = S0 ? 64 : 128;
  constexpr int MSK  = S0 ? 7  : 15;
  const int m15 = lane & 15, g = lane >> 4;
#pragma unroll
  for (int s = 0; s < NSEG; ++s){
    int buf, rb, kb;
    if constexpr (S0){
      buf = (TYPE==0 ? S0TILEB : (TYPE==1 ? S0VRAWB : S0ERAWB)); rb = 0; kb = 0;
    } else {
      kb = s & 1;
      int ab = (TYPE==0 ? 0 : (TYPE==1 ? 19 : 73));
      if (s < 2)      { buf = ACTS; rb = ab; }
      else if (s < 4) { buf = GATA; rb = ab; }
      else            { buf = GATB; rb = 0;  }
    }
    v8s af = load_frag(sm, buf, STR, rb + roff + m15, kb*8 + g, MSK);
    const v8s* w4 = wp + s*256 + lane;
    A.c0 = __builtin_amdgcn_mfma_f32_16x16x32_bf16(af, w4[0],   A.c0, 0, 0, 0);
    A.c1 = __builtin_amdgcn_mfma_f32_16x16x32_bf16(af, w4[64],  A.c1, 0, 0, 0);
    A.c2 = __builtin_amdgcn_mfma_f32_16x16x32_bf16(af, w4[128], A.c2, 0, 0, 0);
    A.c3 = __builtin_amdgcn_mfma_f32_16x16x32_bf16(af, w4[192], A.c3, 0, 0, 0);
  }
}

// LN+ReLU a 16-row tile (C layout: col=l&15, row=4*(l>>4)+q), write bf16 acts.
__device__ __forceinline__ void tile_ln_store(unsigned char* sm, int typeRow0, int Mv, int roff, int lane,
    const float* __restrict__ bp, const float* __restrict__ gp, const float* __restrict__ bep, Acc4& A)
{
  const int cl = lane & 15, g4 = (lane >> 4) << 2;
  const float b0 = bp[cl], b1 = bp[16+cl], b2 = bp[32+cl], b3 = bp[48+cl];
  const float gA = gp[cl], gB = gp[16+cl], gC = gp[32+cl], gD = gp[48+cl];
  const float e0 = bep[cl], e1 = bep[16+cl], e2 = bep[32+cl], e3 = bep[48+cl];
#pragma unroll
  for (int q = 0; q < 4; ++q){
    float y0 = A.c0[q] + b0, y1 = A.c1[q] + b1, y2 = A.c2[q] + b2, y3 = A.c3[q] + b3;
    float mu = red16(y0 + y1 + y2 + y3) * 0.015625f;
    float d0 = y0-mu, d1 = y1-mu, d2 = y2-mu, d3 = y3-mu;
    float var = red16(d0*d0 + d1*d1 + d2*d2 + d3*d3) * 0.015625f;
    float rs = rsqrtf(var + 1e-5f);
    int row = roff + g4 + q;
    if (row < Mv){
      lds_bf_write(sm, ACTS, 128, typeRow0+row,  0+cl, 15, f2bf(fmaxf(fmaf(d0*rs, gA, e0), 0.f)));
      lds_bf_write(sm, ACTS, 128, typeRow0+row, 16+cl, 15, f2bf(fmaxf(fmaf(d1*rs, gB, e1), 0.f)));
      lds_bf_write(sm, ACTS, 128, typeRow0+row, 32+cl, 15, f2bf(fmaxf(fmaf(d2*rs, gC, e2), 0.f)));
      lds_bf_write(sm, ACTS, 128, typeRow0+row, 48+cl, 15, f2bf(fmaxf(fmaf(d3*rs, gD, e3), 0.f)));
    }
  }
}

// ---- prep kernel: pack all W (f32, K x 64) into bf16 B-fragment order ----
__global__ void pack_w_kernel(
    const float* __restrict__ hinW, const float* __restrict__ vinW,
    const float* __restrict__ einW, const float* __restrict__ huW,
    const float* __restrict__ vuW,  const float* __restrict__ euW,
    unsigned short* __restrict__ wp)
{
  int fb = blockIdx.x, l = threadIdx.x;
  const float* W; int s, nt;
  if (fb < 8){
    if (fb < 4){ W = hinW; s = 0; nt = fb; }
    else       { W = vinW; s = 0; nt = fb - 4; }
  } else if (fb < 12){ W = einW; s = 0; nt = fb - 8; }
  else if (fb < 44){ int t = fb - 12; W = huW + (t >> 4)*8192;  int rem = t & 15; s = rem >> 2; nt = rem & 3; }
  else if (fb < 92){ int t = fb - 44; W = vuW + (t / 24)*12288; int rem = t % 24; s = rem >> 2; nt = rem & 3; }
  else             { int t = fb - 92; W = euW + (t >> 4)*8192;  int rem = t & 15; s = rem >> 2; nt = rem & 3; }
  int g4 = (l >> 4) << 2, col = nt*16 + (l & 15);
  unsigned short* dst = wp + ((size_t)fb*64 + l)*8;
#pragma unroll
  for (int j = 0; j < 8; ++j){
    int k = s*32 + ((j >> 2) << 4) + g4 + (j & 3);
    dst[j] = f2bf(W[k*64 + col]);
  }
}

__global__ __launch_bounds__(BLK, 2)
void graph_enc_kernel(
    const float* __restrict__ tile,
    const int* __restrict__ h2v, const int* __restrict__ v2h,
    const int* __restrict__ e2v, const int* __restrict__ v2e,
    const v8s* __restrict__ wpack,
    const float* __restrict__ hinb, const float* __restrict__ hing, const float* __restrict__ hinbe,
    const float* __restrict__ vinb, const float* __restrict__ ving, const float* __restrict__ vinbe,
    const float* __restrict__ einb, const float* __restrict__ eing, const float* __restrict__ einbe,
    const float* __restrict__ hub,  const float* __restrict__ hug,  const float* __restrict__ hube,
    const float* __restrict__ vub,  const float* __restrict__ vug,  const float* __restrict__ vube,
    const float* __restrict__ eub,  const float* __restrict__ eug,  const float* __restrict__ eube,
    const float* __restrict__ roW,  const float* __restrict__ rob,
    const float* __restrict__ rog,  const float* __restrict__ robe,
    float* __restrict__ out)
{
  __shared__ __align__(16) unsigned char sm[49152];
  const int b = blockIdx.x, t = threadIdx.x, lane = t & 63, wv = t >> 6;

  // ---- P0: stage tile features (f32 plain + bf16 swizzled) ----
  const float* tsrc = tile + (size_t)b * 608;
  float* tilef = (float*)(sm + S0TILEF);
  for (int i = t; i < 608; i += BLK){
    float f = tsrc[i];
    tilef[i] = f;
    lds_bf_write(sm, S0TILEB, 64, i >> 5, i & 31, 7, f2bf(f));
  }
  __syncthreads();
  // ---- P1: vertex_raw ----
  {
    float* vrawf = (float*)(sm + S0VRAWF);
    int hr = t >> 5, c = t & 31;
    for (int v = hr; v < 54; v += 16){
      float s = 0.f; int cnt = 0;
#pragma unroll
      for (int j = 0; j < 3; ++j){ int ix = v2h[v*3+j]; if (ix >= 0){ s += tilef[ix*32 + c]; cnt++; } }
      float mval = s / (float)(cnt > 0 ? cnt : 1);
      vrawf[v*32 + c] = mval;
      lds_bf_write(sm, S0VRAWB, 64, v, c, 7, f2bf(mval));
    }
  }
  __syncthreads();
  // ---- P2: edge_raw ----
  {
    const float* vrawf = (const float*)(sm + S0VRAWF);
    int hr = t >> 5, c = t & 31;
    for (int e = hr; e < 72; e += 16){
      float s = 0.f; int cnt = 0;
#pragma unroll
      for (int j = 0; j < 2; ++j){ int ix = e2v[e*2+j]; if (ix >= 0){ s += vrawf[ix*32 + c]; cnt++; } }
      float mval = s / (float)(cnt > 0 ? cnt : 1);
      lds_bf_write(sm, S0ERAWB, 64, e, c, 7, f2bf(mval));
    }
  }
  __syncthreads();

  const v4f zz = {0.f, 0.f, 0.f, 0.f};

  // ---- P3: stage-0 GEMMs (K=32) + LN ----
  {
    const v8s* hinP = wpack + FB_HIN*64;
    const v8s* vinP = wpack + FB_VIN*64;
    const v8s* einP = wpack + FB_EIN*64;
    Acc4 A0; A0.c0 = zz; A0.c1 = zz; A0.c2 = zz; A0.c3 = zz;
    Acc4 A1 = A0;
    switch (wv){
      case 0: tile_accum<0,true>(sm, 0,lane,hinP,A0); tile_accum<0,true>(sm,16,lane,hinP,A1); break;
      case 1: tile_accum<1,true>(sm, 0,lane,vinP,A0); break;
      case 2: tile_accum<1,true>(sm,16,lane,vinP,A0); break;
      case 3: tile_accum<1,true>(sm,32,lane,vinP,A0); break;
      case 4: tile_accum<1,true>(sm,48,lane,vinP,A0); break;
      case 5: tile_accum<2,true>(sm, 0,lane,einP,A0); tile_accum<2,true>(sm,64,lane,einP,A1); break;
      case 6: tile_accum<2,true>(sm,16,lane,einP,A0); tile_accum<2,true>(sm,48,lane,einP,A1); break;
      case 7: tile_accum<2,true>(sm,32,lane,einP,A0); break;
    }
    __syncthreads();
    switch (wv){
      case 0: tile_ln_store(sm, 0,19, 0,lane,hinb,hing,hinbe,A0); tile_ln_store(sm, 0,19,16,lane,hinb,hing,hinbe,A1); break;
      case 1: tile_ln_store(sm,19,54, 0,lane,vinb,ving,vinbe,A0); break;
      case 2: tile_ln_store(sm,19,54,16,lane,vinb,ving,vinbe,A0); break;
      case 3: tile_ln_store(sm,19,54,32,lane,vinb,ving,vinbe,A0); break;
      case 4: tile_ln_store(sm,19,54,48,lane,vinb,ving,vinbe,A0); break;
      case 5: tile_ln_store(sm,73,72, 0,lane,einb,eing,einbe,A0); tile_ln_store(sm,73,72,64,lane,einb,eing,einbe,A1); break;
      case 6: tile_ln_store(sm,73,72,16,lane,einb,eing,einbe,A0); tile_ln_store(sm,73,72,48,lane,einb,eing,einbe,A1); break;
      case 7: tile_ln_store(sm,73,72,32,lane,einb,eing,einbe,A0); break;
    }
  }
  __syncthreads();

  // ---- 2 message-passing rounds ----
  for (int r = 0; r < 2; ++r){
    // P4: gathers (199 rows, wave-strided) from old acts
    for (int gid = wv; gid < 199; gid += 8){
      const int* idx; int deg, srcB, dbase, drow;
      if (gid < 19)      { idx = h2v + gid*6;        deg = 6; srcB = 19; dbase = GATA; drow = gid; }
      else if (gid < 73) { int v = gid-19;  idx = v2h + v*3; deg = 3; srcB = 0;  dbase = GATA; drow = 19+v; }
      else if (gid < 145){ int e = gid-73;  idx = e2v + e*2; deg = 2; srcB = 19; dbase = GATA; drow = 73+e; }
      else               { int v = gid-145; idx = v2e + v*3; deg = 3; srcB = 73; dbase = GATB; drow = v; }
      float s = 0.f; int cnt = 0;
      for (int j = 0; j < deg; ++j){
        int ix = idx[j];
        if (ix >= 0){ s += bf2f(lds_bf_read(sm, ACTS, 128, srcB+ix, lane, 15)); cnt++; }
      }
      float mval = s / (float)(cnt > 0 ? cnt : 1);
      lds_bf_write(sm, dbase, 128, drow, lane, 15, f2bf(mval));
    }
    __syncthreads();
    // P5: GEMM accumulate (reads old acts + gathers; no LDS writes)
    const v8s* huP = wpack + (FB_HU + r*16)*64;
    const v8s* vuP = wpack + (FB_VU + r*24)*64;
    const v8s* euP = wpack + (FB_EU + r*16)*64;
    Acc4 A0; A0.c0 = zz; A0.c1 = zz; A0.c2 = zz; A0.c3 = zz;
    Acc4 A1 = A0;
    switch (wv){
      case 0: tile_accum<0,false>(sm, 0,lane,huP,A0); tile_accum<0,false>(sm,16,lane,huP,A1); break;
      case 1: tile_accum<1,false>(sm, 0,lane,vuP,A0); break;
      case 2: tile_accum<1,false>(sm,16,lane,vuP,A0); break;
      case 3: tile_accum<1,false>(sm,32,lane,vuP,A0); break;
      case 4: tile_accum<1,false>(sm,48,lane,vuP,A0); break;
      case 5: tile_accum<2,false>(sm, 0,lane,euP,A0); tile_accum<2,false>(sm,64,lane,euP,A1); break;
      case 6: tile_accum<2,false>(sm,16,lane,euP,A0); tile_accum<2,false>(sm,48,lane,euP,A1); break;
      case 7: tile_accum<2,false>(sm,32,lane,euP,A0); break;
    }
    __syncthreads();
    // P6: LN + writeback
    const float *hub_r = hub + r*64, *hug_r = hug + r*64, *hube_r = hube + r*64;
    const float *vub_r = vub + r*64, *vug_r = vug + r*64, *vube_r = vube + r*64;
    const float *eub_r = eub + r*64, *eug_r = eug + r*64, *eube_r = eube + r*64;
    switch (wv){
      case 0: tile_ln_store(sm, 0,19, 0,lane,hub_r,hug_r,hube_r,A0); tile_ln_store(sm, 0,19,16,lane,hub_r,hug_r,hube_r,A1); break;
      case 1: tile_ln_store(sm,19,54, 0,lane,vub_r,vug_r,vube_r,A0); break;
      case 2: tile_ln_store(sm,19,54,16,lane,vub_r,vug_r,vube_r,A0); break;
      case 3: tile_ln_store(sm,19,54,32,lane,vub_r,vug_r,vube_r,A0); break;
      case 4: tile_ln_store(sm,19,54,48,lane,vub_r,vug_r,vube_r,A0); break;
      case 5: tile_ln_store(sm,73,72, 0,lane,eub_r,eug_r,eube_r,A0); tile_ln_store(sm,73,72,64,lane,eub_r,eug_r,eube_r,A1); break;
      case 6: tile_ln_store(sm,73,72,16,lane,eub_r,eug_r,eube_r,A0); tile_ln_store(sm,73,72,48,lane,eub_r,eug_r,eube_r,A1); break;
      case 7: tile_ln_store(sm,73,72,32,lane,eub_r,eug_r,eube_r,A0); break;
    }
    __syncthreads();
  }

  // ---- P7: pooling (waves 0-2) + zero readout acc (wave 3) ----
  if (wv < 3){
    int R  = (wv == 0 ? 19 : (wv == 1 ? 54 : 72));
    int B0 = (wv == 0 ? 0  : (wv == 1 ? 19 : 73));
    float s = 0.f;
    for (int n = 0; n < R; ++n) s += bf2f(lds_bf_read(sm, ACTS, 128, B0+n, lane, 15));
    ((float*)(sm + POOLF))[wv*64 + lane] = s / (float)R;
  } else if (wv == 3){
    ((float*)(sm + RACC))[lane] = 0.f;
  }
  __syncthreads();
  // ---- P8: readout partials (waves 0-3, 48 K each) ----
  if (wv < 4){
    const float* pool = (const float*)(sm + POOLF);
    float s0 = 0.f, s1 = 0.f, s2 = 0.f, s3 = 0.f;
#pragma unroll 4
    for (int kk = 0; kk < 48; kk += 4){
      int k = wv*48 + kk;
      s0 = fmaf(pool[k+0], roW[(size_t)(k+0)*64 + lane], s0);
      s1 = fmaf(pool[k+1], roW[(size_t)(k+1)*64 + lane], s1);
      s2 = fmaf(pool[k+2], roW[(size_t)(k+2)*64 + lane], s2);
      s3 = fmaf(pool[k+3], roW[(size_t)(k+3)*64 + lane], s3);
    }
    atomicAdd((float*)(sm + RACC) + lane, (s0+s1) + (s2+s3));
  }
  __syncthreads();
  // ---- P9: readout LN (wave 0) ----
  if (wv == 0){
    float v = ((float*)(sm + RACC))[lane] + rob[lane];
    float mu = red64(v) * 0.015625f;
    float d = v - mu;
    float var = red64(d*d) * 0.015625f;
    float y = fmaf(d * rsqrtf(var + 1e-5f), rog[lane], robe[lane]);
    out[(size_t)b*64 + lane] = fmaxf(y, 0.f);
  }
}

extern "C" void kernel_launch(void* const* d_in, const int* in_sizes, int n_in,
                              void* d_out, int out_size, void* d_ws, size_t ws_size,
                              hipStream_t stream) {
  const float* tile = (const float*)d_in[0];
  const int* h2v  = (const int*)d_in[1];
  const int* v2h  = (const int*)d_in[2];
  const int* e2v  = (const int*)d_in[3];
  const int* v2e  = (const int*)d_in[4];
  const float* hinW = (const float*)d_in[5];
  const float* hinb = (const float*)d_in[6];
  const float* hing = (const float*)d_in[7];
  const float* hinbe= (const float*)d_in[8];
  const float* vinW = (const float*)d_in[9];
  const float* vinb = (const float*)d_in[10];
  const float* ving = (const float*)d_in[11];
  const float* vinbe= (const float*)d_in[12];
  const float* einW = (const float*)d_in[13];
  const float* einb = (const float*)d_in[14];
  const float* eing = (const float*)d_in[15];
  const float* einbe= (const float*)d_in[16];
  const float* huW  = (const float*)d_in[17];
  const float* hub  = (const float*)d_in[18];
  const float* hug  = (const float*)d_in[19];
  const float* hube = (const float*)d_in[20];
  const float* vuW  = (const float*)d_in[21];
  const float* vub  = (const float*)d_in[22];
  const float* vug  = (const float*)d_in[23];
  const float* vube = (const float*)d_in[24];
  const float* euW  = (const float*)d_in[25];
  const float* eub  = (const float*)d_in[26];
  const float* eug  = (const float*)d_in[27];
  const float* eube = (const float*)d_in[28];
  const float* roW  = (const float*)d_in[29];
  const float* rob  = (const float*)d_in[30];
  const float* rog  = (const float*)d_in[31];
  const float* robe = (const float*)d_in[32];
  float* out = (float*)d_out;

  unsigned short* wpack = (unsigned short*)d_ws;   // 124 KB used

  hipLaunchKernelGGL(pack_w_kernel, dim3(NFB), dim3(64), 0, stream,
      hinW, vinW, einW, huW, vuW, euW, wpack);

  int B = in_sizes[0] / 608;   // 16384
  hipLaunchKernelGGL(graph_enc_kernel, dim3(B), dim3(BLK), 0, stream,
      tile, h2v, v2h, e2v, v2e,
      (const v8s*)wpack,
      hinb, hing, hinbe,
      vinb, ving, vinbe,
      einb, eing, einbe,
      hub, hug, hube,
      vub, vug, vube,
      eub, eug, eube,
      roW, rob, rog, robe,
      out);
}

// Round 8
// 3259.570 us; speedup vs baseline: 1.1163x; 1.1163x over previous
//
#include <hip/hip_runtime.h>

// Fused per-batch graph encoder, v8: MFMA bf16 + packed weights.
// 704 threads (11 waves)/block = one 16-row output tile per wave per phase.
// Ping-pong ACTS buffers; barrier after every phase; ALL readable LDS
// zero-initialized at start (no uninit reads, no in-place hazards).

#define BLK 704

typedef short v4s __attribute__((ext_vector_type(4)));
typedef short v8s __attribute__((ext_vector_type(8)));
typedef float v4f __attribute__((ext_vector_type(4)));

// byte offsets into the 69632-B shared block
#define ACTS0   0              // 160 rows x 128B bf16, swz mask 15
#define ACTS1   20480
#define GATA    40960          // 160 rows x 128B (h_from_v / v_from_h / e_from_v)
#define GATB    61440          // 64 rows x 128B (v_from_e)
#define SMBYTES 69632
// stage-0 overlays (inside GATA/GATB; free until the rounds)
#define S0TILEF (GATA + 0)     // 19x32 f32
#define S0VRAWF (GATA + 2432)  // 54x32 f32
#define S0TILEB (GATA + 9344)  // 32 rows x 64B bf16, swz mask 7
#define S0VRAWB (GATA + 11392) // 64 rows x 64B
#define S0ERAWB (GATB + 0)     // 80 rows x 64B
// post-round overlays (GATA read is barrier-separated)
#define POOLF   (GATA + 0)     // 192 f32
#define RACC    (GATA + 768)   // 64 f32

// packed-W frag-block bases (1 block = 64 lanes x 8 bf16 = 1KB)
#define FB_HIN 0
#define FB_VIN 4
#define FB_EIN 8
#define FB_HU  12   // +16 per round
#define FB_VU  44   // +24 per round
#define FB_EU  92   // +16 per round
#define NFB    124

struct Acc4 { v4f c0, c1, c2, c3; };

__device__ __forceinline__ unsigned short f2bf(float f){
  unsigned u = __float_as_uint(f);
  return (unsigned short)((u + 0x7fffu + ((u >> 16) & 1u)) >> 16);
}
__device__ __forceinline__ float bf2f(unsigned short h){
  return __uint_as_float(((unsigned)h) << 16);
}

__device__ __forceinline__ float red16(float v){
  v += __shfl_xor(v, 1, 64);
  v += __shfl_xor(v, 2, 64);
  v += __shfl_xor(v, 4, 64);
  v += __shfl_xor(v, 8, 64);
  return v;
}
__device__ __forceinline__ float red64(float v){
#pragma unroll
  for (int m = 32; m >= 1; m >>= 1) v += __shfl_xor(v, m, 64);
  return v;
}

__device__ __forceinline__ int swz_off(int base, int stride, int row, int col, int m){
  return base + row*stride + ((((col >> 2) ^ (row & m)) << 3) + ((col & 3) << 1));
}
__device__ __forceinline__ unsigned short lds_bf_read(const unsigned char* sm, int base, int stride, int row, int col, int m){
  return *(const unsigned short*)(sm + swz_off(base, stride, row, col, m));
}
__device__ __forceinline__ void lds_bf_write(unsigned char* sm, int base, int stride, int row, int col, int m, unsigned short v){
  *(unsigned short*)(sm + swz_off(base, stride, row, col, m)) = v;
}

// A-fragment: lane l row=(l&15), k(j) = 32*seg + 16*(j>>2) + 4*(l>>4) + (j&3).
__device__ __forceinline__ v8s load_frag(const unsigned char* sm, int base, int stride, int row, int cb, int m){
  v4s lo = *(const v4s*)(sm + base + row*stride + (((cb    ) ^ (row & m)) << 3));
  v4s hi = *(const v4s*)(sm + base + row*stride + (((cb + 4) ^ (row & m)) << 3));
  v8s r; r[0]=lo[0]; r[1]=lo[1]; r[2]=lo[2]; r[3]=lo[3]; r[4]=hi[0]; r[5]=hi[1]; r[6]=hi[2]; r[7]=hi[3];
  return r;
}

// TYPE: 0=hex 1=vtx 2=edge. S0: stage-0 (K=32). Straight-line:
// accumulate + LN + store to actsDst (never read in this phase).
template<int TYPE, bool S0>
__device__ __forceinline__ void do_tile(unsigned char* sm, int actsSrc, int actsDst,
    int roff, int lane, const v8s* __restrict__ wp,
    const float* __restrict__ bp, const float* __restrict__ gp, const float* __restrict__ bep)
{
  constexpr int NSEG = S0 ? 1 : (TYPE == 1 ? 6 : 4);
  constexpr int STR  = S0 ? 64 : 128;
  constexpr int MSK  = S0 ? 7  : 15;
  constexpr int TR0  = (TYPE==0 ? 0 : (TYPE==1 ? 19 : 73));
  constexpr int MV   = (TYPE==0 ? 19 : (TYPE==1 ? 54 : 72));
  const int m15 = lane & 15, g = lane >> 4;

  const v4f zz = {0.f, 0.f, 0.f, 0.f};
  Acc4 A; A.c0 = zz; A.c1 = zz; A.c2 = zz; A.c3 = zz;

#pragma unroll
  for (int s = 0; s < NSEG; ++s){
    int buf, rb, kb;
    if constexpr (S0){
      buf = (TYPE==0 ? S0TILEB : (TYPE==1 ? S0VRAWB : S0ERAWB)); rb = 0; kb = 0;
    } else {
      kb = s & 1;
      if (s < 2)      { buf = actsSrc; rb = TR0; }
      else if (s < 4) { buf = GATA;    rb = TR0; }
      else            { buf = GATB;    rb = 0;   }
    }
    v8s af = load_frag(sm, buf, STR, rb + roff + m15, kb*8 + g, MSK);
    const v8s* w4 = wp + s*256 + lane;
    A.c0 = __builtin_amdgcn_mfma_f32_16x16x32_bf16(af, w4[0],   A.c0, 0, 0, 0);
    A.c1 = __builtin_amdgcn_mfma_f32_16x16x32_bf16(af, w4[64],  A.c1, 0, 0, 0);
    A.c2 = __builtin_amdgcn_mfma_f32_16x16x32_bf16(af, w4[128], A.c2, 0, 0, 0);
    A.c3 = __builtin_amdgcn_mfma_f32_16x16x32_bf16(af, w4[192], A.c3, 0, 0, 0);
  }

  // LN + ReLU + bf16 store (C layout: col=l&15, row=4*(l>>4)+q)
  const int cl = m15, g4 = g << 2;
  const float b0 = bp[cl], b1 = bp[16+cl], b2 = bp[32+cl], b3 = bp[48+cl];
  const float gA = gp[cl], gB = gp[16+cl], gC = gp[32+cl], gD = gp[48+cl];
  const float e0 = bep[cl], e1 = bep[16+cl], e2 = bep[32+cl], e3 = bep[48+cl];
#pragma unroll
  for (int q = 0; q < 4; ++q){
    float y0 = A.c0[q] + b0, y1 = A.c1[q] + b1, y2 = A.c2[q] + b2, y3 = A.c3[q] + b3;
    float mu = red16(y0 + y1 + y2 + y3) * 0.015625f;
    float d0 = y0-mu, d1 = y1-mu, d2 = y2-mu, d3 = y3-mu;
    float var = red16(d0*d0 + d1*d1 + d2*d2 + d3*d3) * 0.015625f;
    float rs = rsqrtf(var + 1e-5f);
    int row = roff + g4 + q;
    if (row < MV){
      lds_bf_write(sm, actsDst, 128, TR0+row,  0+cl, 15, f2bf(fmaxf(fmaf(d0*rs, gA, e0), 0.f)));
      lds_bf_write(sm, actsDst, 128, TR0+row, 16+cl, 15, f2bf(fmaxf(fmaf(d1*rs, gB, e1), 0.f)));
      lds_bf_write(sm, actsDst, 128, TR0+row, 32+cl, 15, f2bf(fmaxf(fmaf(d2*rs, gC, e2), 0.f)));
      lds_bf_write(sm, actsDst, 128, TR0+row, 48+cl, 15, f2bf(fmaxf(fmaf(d3*rs, gD, e3), 0.f)));
    }
  }
}

// ---- prep kernel: pack all W (f32, K x 64) into bf16 B-fragment order ----
__global__ void pack_w_kernel(
    const float* __restrict__ hinW, const float* __restrict__ vinW,
    const float* __restrict__ einW, const float* __restrict__ huW,
    const float* __restrict__ vuW,  const float* __restrict__ euW,
    unsigned short* __restrict__ wp)
{
  int fb = blockIdx.x, l = threadIdx.x;
  const float* W; int s, nt;
  if (fb < 8){
    if (fb < 4){ W = hinW; s = 0; nt = fb; }
    else       { W = vinW; s = 0; nt = fb - 4; }
  } else if (fb < 12){ W = einW; s = 0; nt = fb - 8; }
  else if (fb < 44){ int t = fb - 12; W = huW + (t >> 4)*8192;  int rem = t & 15; s = rem >> 2; nt = rem & 3; }
  else if (fb < 92){ int t = fb - 44; W = vuW + (t / 24)*12288; int rem = t % 24; s = rem >> 2; nt = rem & 3; }
  else             { int t = fb - 92; W = euW + (t >> 4)*8192;  int rem = t & 15; s = rem >> 2; nt = rem & 3; }
  int g4 = (l >> 4) << 2, col = nt*16 + (l & 15);
  unsigned short* dst = wp + ((size_t)fb*64 + l)*8;
#pragma unroll
  for (int j = 0; j < 8; ++j){
    int k = s*32 + ((j >> 2) << 4) + g4 + (j & 3);
    dst[j] = f2bf(W[k*64 + col]);
  }
}

__global__ __launch_bounds__(BLK, 5)
void graph_enc_kernel(
    const float* __restrict__ tile,
    const int* __restrict__ h2v, const int* __restrict__ v2h,
    const int* __restrict__ e2v, const int* __restrict__ v2e,
    const v8s* __restrict__ wpack,
    const float* __restrict__ hinb, const float* __restrict__ hing, const float* __restrict__ hinbe,
    const float* __restrict__ vinb, const float* __restrict__ ving, const float* __restrict__ vinbe,
    const float* __restrict__ einb, const float* __restrict__ eing, const float* __restrict__ einbe,
    const float* __restrict__ hub,  const float* __restrict__ hug,  const float* __restrict__ hube,
    const float* __restrict__ vub,  const float* __restrict__ vug,  const float* __restrict__ vube,
    const float* __restrict__ eub,  const float* __restrict__ eug,  const float* __restrict__ eube,
    const float* __restrict__ roW,  const float* __restrict__ rob,
    const float* __restrict__ rog,  const float* __restrict__ robe,
    float* __restrict__ out)
{
  __shared__ __align__(16) unsigned char sm[SMBYTES];
  const int b = blockIdx.x, t = threadIdx.x, lane = t & 63, wv = t >> 6;

  // ---- Pz: zero-init every LDS byte that is ever read before being
  // written: all of GATA+GATB (incl. S0 overlay tails) + ACTS tails ----
  {
    unsigned int* z = (unsigned int*)sm;
    for (int i = 10240 + t; i < 17408; i += BLK) z[i] = 0u;          // GATA+GATB
    for (int i = 4640 + t;  i < 5120;  i += BLK) z[i] = 0u;          // ACTS0 rows 145-159
    for (int i = 9760 + t;  i < 10240; i += BLK) z[i] = 0u;          // ACTS1 rows 145-159
  }
  __syncthreads();

  // ---- P0: stage tile features (f32 plain + bf16 swizzled) ----
  const float* tsrc = tile + (size_t)b * 608;
  float* tilef = (float*)(sm + S0TILEF);
  for (int i = t; i < 608; i += BLK){
    float f = tsrc[i];
    tilef[i] = f;
    lds_bf_write(sm, S0TILEB, 64, i >> 5, i & 31, 7, f2bf(f));
  }
  __syncthreads();
  // ---- P1: vertex_raw ----
  {
    float* vrawf = (float*)(sm + S0VRAWF);
    int hr = t >> 5, c = t & 31;
    for (int v = hr; v < 54; v += 22){
      float s = 0.f; int cnt = 0;
#pragma unroll
      for (int j = 0; j < 3; ++j){ int ix = v2h[v*3+j]; if (ix >= 0){ s += tilef[ix*32 + c]; cnt++; } }
      float mval = s / (float)(cnt > 0 ? cnt : 1);
      vrawf[v*32 + c] = mval;
      lds_bf_write(sm, S0VRAWB, 64, v, c, 7, f2bf(mval));
    }
  }
  __syncthreads();
  // ---- P2: edge_raw ----
  {
    const float* vrawf = (const float*)(sm + S0VRAWF);
    int hr = t >> 5, c = t & 31;
    for (int e = hr; e < 72; e += 22){
      float s = 0.f; int cnt = 0;
#pragma unroll
      for (int j = 0; j < 2; ++j){ int ix = e2v[e*2+j]; if (ix >= 0){ s += vrawf[ix*32 + c]; cnt++; } }
      float mval = s / (float)(cnt > 0 ? cnt : 1);
      lds_bf_write(sm, S0ERAWB, 64, e, c, 7, f2bf(mval));
    }
  }
  __syncthreads();

  // ---- P3: stage-0 GEMMs (K=32) + LN -> ACTS0. One tile per wave. ----
  {
    const v8s* hinP = wpack + FB_HIN*64;
    const v8s* vinP = wpack + FB_VIN*64;
    const v8s* einP = wpack + FB_EIN*64;
    if (wv < 2)       do_tile<0,true>(sm, 0, ACTS0, wv*16,      lane, hinP, hinb, hing, hinbe);
    else if (wv < 6)  do_tile<1,true>(sm, 0, ACTS0, (wv-2)*16,  lane, vinP, vinb, ving, vinbe);
    else              do_tile<2,true>(sm, 0, ACTS0, (wv-6)*16,  lane, einP, einb, eing, einbe);
  }
  __syncthreads();

  // ---- 2 message-passing rounds (acts ping-pong) ----
#pragma unroll
  for (int r = 0; r < 2; ++r){
    const int src = r ? ACTS1 : ACTS0;
    const int dst = r ? ACTS0 : ACTS1;
    // P4: gathers (199 rows, wave-strided) read src acts -> GATA/GATB
    for (int gid = wv; gid < 199; gid += 11){
      const int* idx; int deg, srcB, dbase, drow;
      if (gid < 19)      { idx = h2v + gid*6;        deg = 6; srcB = 19; dbase = GATA; drow = gid; }
      else if (gid < 73) { int v = gid-19;  idx = v2h + v*3; deg = 3; srcB = 0;  dbase = GATA; drow = 19+v; }
      else if (gid < 145){ int e = gid-73;  idx = e2v + e*2; deg = 2; srcB = 19; dbase = GATA; drow = 73+e; }
      else               { int v = gid-145; idx = v2e + v*3; deg = 3; srcB = 73; dbase = GATB; drow = v; }
      float s = 0.f; int cnt = 0;
      for (int j = 0; j < deg; ++j){
        int ix = idx[j];
        if (ix >= 0){ s += bf2f(lds_bf_read(sm, src, 128, srcB+ix, lane, 15)); cnt++; }
      }
      float mval = s / (float)(cnt > 0 ? cnt : 1);
      lds_bf_write(sm, dbase, 128, drow, lane, 15, f2bf(mval));
    }
    __syncthreads();
    // P5: one tile per wave: reads src(own rows)+GATA/GATB, writes dst
    const v8s* huP = wpack + (FB_HU + r*16)*64;
    const v8s* vuP = wpack + (FB_VU + r*24)*64;
    const v8s* euP = wpack + (FB_EU + r*16)*64;
    if (wv < 2)       do_tile<0,false>(sm, src, dst, wv*16,     lane, huP, hub + r*64, hug + r*64, hube + r*64);
    else if (wv < 6)  do_tile<1,false>(sm, src, dst, (wv-2)*16, lane, vuP, vub + r*64, vug + r*64, vube + r*64);
    else              do_tile<2,false>(sm, src, dst, (wv-6)*16, lane, euP, eub + r*64, eug + r*64, eube + r*64);
    __syncthreads();
  }

  // ---- P7: pooling (waves 0-2, read ACTS0) + zero readout acc (wave 3) ----
  if (wv < 3){
    int R  = (wv == 0 ? 19 : (wv == 1 ? 54 : 72));
    int B0 = (wv == 0 ? 0  : (wv == 1 ? 19 : 73));
    float s = 0.f;
    for (int n = 0; n < R; ++n) s += bf2f(lds_bf_read(sm, ACTS0, 128, B0+n, lane, 15));
    ((float*)(sm + POOLF))[wv*64 + lane] = s / (float)R;
  } else if (wv == 3){
    ((float*)(sm + RACC))[lane] = 0.f;
  }
  __syncthreads();
  // ---- P8: readout partials (waves 0-3, 48 K each) ----
  if (wv < 4){
    const float* pool = (const float*)(sm + POOLF);
    float s0 = 0.f, s1 = 0.f, s2 = 0.f, s3 = 0.f;
#pragma unroll 4
    for (int kk = 0; kk < 48; kk += 4){
      int k = wv*48 + kk;
      s0 = fmaf(pool[k+0], roW[(size_t)(k+0)*64 + lane], s0);
      s1 = fmaf(pool[k+1], roW[(size_t)(k+1)*64 + lane], s1);
      s2 = fmaf(pool[k+2], roW[(size_t)(k+2)*64 + lane], s2);
      s3 = fmaf(pool[k+3], roW[(size_t)(k+3)*64 + lane], s3);
    }
    atomicAdd((float*)(sm + RACC) + lane, (s0+s1) + (s2+s3));
  }
  __syncthreads();
  // ---- P9: readout LN (wave 0) ----
  if (wv == 0){
    float v = ((float*)(sm + RACC))[lane] + rob[lane];
    float mu = red64(v) * 0.015625f;
    float d = v - mu;
    float var = red64(d*d) * 0.015625f;
    float y = fmaf(d * rsqrtf(var + 1e-5f), rog[lane], robe[lane]);
    out[(size_t)b*64 + lane] = fmaxf(y, 0.f);
  }
}

extern "C" void kernel_launch(void* const* d_in, const int* in_sizes, int n_in,
                              void* d_out, int out_size, void* d_ws, size_t ws_size,
                              hipStream_t stream) {
  const float* tile = (const float*)d_in[0];
  const int* h2v  = (const int*)d_in[1];
  const int* v2h  = (const int*)d_in[2];
  const int* e2v  = (const int*)d_in[3];
  const int* v2e  = (const int*)d_in[4];
  const float* hinW = (const float*)d_in[5];
  const float* hinb = (const float*)d_in[6];
  const float* hing = (const float*)d_in[7];
  const float* hinbe= (const float*)d_in[8];
  const float* vinW = (const float*)d_in[9];
  const float* vinb = (const float*)d_in[10];
  const float* ving = (const float*)d_in[11];
  const float* vinbe= (const float*)d_in[12];
  const float* einW = (const float*)d_in[13];
  const float* einb = (const float*)d_in[14];
  const float* eing = (const float*)d_in[15];
  const float* einbe= (const float*)d_in[16];
  const float* huW  = (const float*)d_in[17];
  const float* hub  = (const float*)d_in[18];
  const float* hug  = (const float*)d_in[19];
  const float* hube = (const float*)d_in[20];
  const float* vuW  = (const float*)d_in[21];
  const float* vub  = (const float*)d_in[22];
  const float* vug  = (const float*)d_in[23];
  const float* vube = (const float*)d_in[24];
  const float* euW  = (const float*)d_in[25];
  const float* eub  = (const float*)d_in[26];
  const float* eug  = (const float*)d_in[27];
  const float* eube = (const float*)d_in[28];
  const float* roW  = (const float*)d_in[29];
  const float* rob  = (const float*)d_in[30];
  const float* rog  = (const float*)d_in[31];
  const float* robe = (const float*)d_in[32];
  float* out = (float*)d_out;

  unsigned short* wpack = (unsigned short*)d_ws;   // 124 KB used

  hipLaunchKernelGGL(pack_w_kernel, dim3(NFB), dim3(64), 0, stream,
      hinW, vinW, einW, huW, vuW, euW, wpack);

  int B = in_sizes[0] / 608;   // 16384
  hipLaunchKernelGGL(graph_enc_kernel, dim3(B), dim3(BLK), 0, stream,
      tile, h2v, v2h, e2v, v2e,
      (const v8s*)wpack,
      hinb, hing, hinbe,
      vinb, ving, vinbe,
      einb, eing, einbe,
      hub, hug, hube,
      vub, vug, vube,
      eub, eug, eube,
      roW, rob, rog, robe,
      out);
}

// Round 9
// 2644.987 us; speedup vs baseline: 1.3757x; 1.2324x over previous
//
#include <hip/hip_runtime.h>

// Fused per-batch graph encoder, v9: MFMA bf16 + packed weights.
// 704 threads (11 waves)/block = one 16-row output tile per wave per phase.
// SINGLE-buffered ACTS (in-place P5 update is race-free: each wave reads only
// its own rows + barrier-protected gather buffers; ds ops are wave-ordered).
// sched_barrier(0) per K-seg stops the scheduler hoisting all W-frag global
// loads (the round-8 spill source). 48KB LDS -> 2 blocks/CU.

#define BLK 704

typedef short v4s __attribute__((ext_vector_type(4)));
typedef short v8s __attribute__((ext_vector_type(8)));
typedef float v4f __attribute__((ext_vector_type(4)));

// byte offsets into the 49152-B shared block
#define ACTS    0              // 160 rows x 128B bf16, swz mask 15
#define GATA    20480          // 160 rows x 128B (h_from_v / v_from_h / e_from_v)
#define GATB    40960          // 64 rows x 128B (v_from_e)
#define SMBYTES 49152
// stage-0 overlays (inside GATA/GATB; free until the rounds)
#define S0TILEF (GATA + 0)     // 19x32 f32
#define S0VRAWF (GATA + 2432)  // 54x32 f32
#define S0TILEB (GATA + 9344)  // 32 rows x 64B bf16, swz mask 7
#define S0VRAWB (GATA + 11392) // 64 rows x 64B
#define S0ERAWB (GATB + 0)     // 80 rows x 64B
// post-round overlays (GATA dead by then; barrier-separated)
#define POOLF   (GATA + 0)     // 192 f32
#define RACC    (GATA + 768)   // 64 f32

// packed-W frag-block bases (1 block = 64 lanes x 8 bf16 = 1KB)
#define FB_HIN 0
#define FB_VIN 4
#define FB_EIN 8
#define FB_HU  12   // +16 per round
#define FB_VU  44   // +24 per round
#define FB_EU  92   // +16 per round
#define NFB    124

struct Acc4 { v4f c0, c1, c2, c3; };

__device__ __forceinline__ unsigned short f2bf(float f){
  unsigned u = __float_as_uint(f);
  return (unsigned short)((u + 0x7fffu + ((u >> 16) & 1u)) >> 16);
}
__device__ __forceinline__ float bf2f(unsigned short h){
  return __uint_as_float(((unsigned)h) << 16);
}

__device__ __forceinline__ float red16(float v){
  v += __shfl_xor(v, 1, 64);
  v += __shfl_xor(v, 2, 64);
  v += __shfl_xor(v, 4, 64);
  v += __shfl_xor(v, 8, 64);
  return v;
}
__device__ __forceinline__ float red64(float v){
#pragma unroll
  for (int m = 32; m >= 1; m >>= 1) v += __shfl_xor(v, m, 64);
  return v;
}

__device__ __forceinline__ int swz_off(int base, int stride, int row, int col, int m){
  return base + row*stride + ((((col >> 2) ^ (row & m)) << 3) + ((col & 3) << 1));
}
__device__ __forceinline__ unsigned short lds_bf_read(const unsigned char* sm, int base, int stride, int row, int col, int m){
  return *(const unsigned short*)(sm + swz_off(base, stride, row, col, m));
}
__device__ __forceinline__ void lds_bf_write(unsigned char* sm, int base, int stride, int row, int col, int m, unsigned short v){
  *(unsigned short*)(sm + swz_off(base, stride, row, col, m)) = v;
}

// A-fragment: lane l row=(l&15), k(j) = 32*seg + 16*(j>>2) + 4*(l>>4) + (j&3).
__device__ __forceinline__ v8s load_frag(const unsigned char* sm, int base, int stride, int row, int cb, int m){
  v4s lo = *(const v4s*)(sm + base + row*stride + (((cb    ) ^ (row & m)) << 3));
  v4s hi = *(const v4s*)(sm + base + row*stride + (((cb + 4) ^ (row & m)) << 3));
  v8s r; r[0]=lo[0]; r[1]=lo[1]; r[2]=lo[2]; r[3]=lo[3]; r[4]=hi[0]; r[5]=hi[1]; r[6]=hi[2]; r[7]=hi[3];
  return r;
}

// TYPE: 0=hex 1=vtx 2=edge. S0: stage-0 (K=32). Straight-line:
// accumulate + LN + in-place store (own rows only).
template<int TYPE, bool S0>
__device__ __forceinline__ void do_tile(unsigned char* sm,
    int roff, int lane, const v8s* __restrict__ wp,
    const float* __restrict__ bp, const float* __restrict__ gp, const float* __restrict__ bep)
{
  constexpr int NSEG = S0 ? 1 : (TYPE == 1 ? 6 : 4);
  constexpr int STR  = S0 ? 64 : 128;
  constexpr int MSK  = S0 ? 7  : 15;
  constexpr int TR0  = (TYPE==0 ? 0 : (TYPE==1 ? 19 : 73));
  constexpr int MV   = (TYPE==0 ? 19 : (TYPE==1 ? 54 : 72));
  const int m15 = lane & 15, g = lane >> 4;

  const v4f zz = {0.f, 0.f, 0.f, 0.f};
  Acc4 A; A.c0 = zz; A.c1 = zz; A.c2 = zz; A.c3 = zz;

#pragma unroll
  for (int s = 0; s < NSEG; ++s){
    int buf, rb, kb;
    if constexpr (S0){
      buf = (TYPE==0 ? S0TILEB : (TYPE==1 ? S0VRAWB : S0ERAWB)); rb = 0; kb = 0;
    } else {
      kb = s & 1;
      if (s < 2)      { buf = ACTS; rb = TR0; }
      else if (s < 4) { buf = GATA; rb = TR0; }
      else            { buf = GATB; rb = 0;   }
    }
    v8s af = load_frag(sm, buf, STR, rb + roff + m15, kb*8 + g, MSK);
    const v8s* w4 = wp + s*256 + lane;
    A.c0 = __builtin_amdgcn_mfma_f32_16x16x32_bf16(af, w4[0],   A.c0, 0, 0, 0);
    A.c1 = __builtin_amdgcn_mfma_f32_16x16x32_bf16(af, w4[64],  A.c1, 0, 0, 0);
    A.c2 = __builtin_amdgcn_mfma_f32_16x16x32_bf16(af, w4[128], A.c2, 0, 0, 0);
    A.c3 = __builtin_amdgcn_mfma_f32_16x16x32_bf16(af, w4[192], A.c3, 0, 0, 0);
    // Stop the scheduler hoisting the next seg's 4 global W-frag loads above
    // this point (round-8 spill source: 24 in-flight dwordx4 -> MAXLIVE blowup).
    __builtin_amdgcn_sched_barrier(0);
  }

  // LN + ReLU + bf16 store (C layout: col=l&15, row=4*(l>>4)+q)
  const int cl = m15, g4 = g << 2;
  const float b0 = bp[cl], b1 = bp[16+cl], b2 = bp[32+cl], b3 = bp[48+cl];
  const float gA = gp[cl], gB = gp[16+cl], gC = gp[32+cl], gD = gp[48+cl];
  const float e0 = bep[cl], e1 = bep[16+cl], e2 = bep[32+cl], e3 = bep[48+cl];
#pragma unroll
  for (int q = 0; q < 4; ++q){
    float y0 = A.c0[q] + b0, y1 = A.c1[q] + b1, y2 = A.c2[q] + b2, y3 = A.c3[q] + b3;
    float mu = red16(y0 + y1 + y2 + y3) * 0.015625f;
    float d0 = y0-mu, d1 = y1-mu, d2 = y2-mu, d3 = y3-mu;
    float var = red16(d0*d0 + d1*d1 + d2*d2 + d3*d3) * 0.015625f;
    float rs = rsqrtf(var + 1e-5f);
    int row = roff + g4 + q;
    if (row < MV){
      lds_bf_write(sm, ACTS, 128, TR0+row,  0+cl, 15, f2bf(fmaxf(fmaf(d0*rs, gA, e0), 0.f)));
      lds_bf_write(sm, ACTS, 128, TR0+row, 16+cl, 15, f2bf(fmaxf(fmaf(d1*rs, gB, e1), 0.f)));
      lds_bf_write(sm, ACTS, 128, TR0+row, 32+cl, 15, f2bf(fmaxf(fmaf(d2*rs, gC, e2), 0.f)));
      lds_bf_write(sm, ACTS, 128, TR0+row, 48+cl, 15, f2bf(fmaxf(fmaf(d3*rs, gD, e3), 0.f)));
    }
  }
}

// ---- prep kernel: pack all W (f32, K x 64) into bf16 B-fragment order ----
__global__ void pack_w_kernel(
    const float* __restrict__ hinW, const float* __restrict__ vinW,
    const float* __restrict__ einW, const float* __restrict__ huW,
    const float* __restrict__ vuW,  const float* __restrict__ euW,
    unsigned short* __restrict__ wp)
{
  int fb = blockIdx.x, l = threadIdx.x;
  const float* W; int s, nt;
  if (fb < 8){
    if (fb < 4){ W = hinW; s = 0; nt = fb; }
    else       { W = vinW; s = 0; nt = fb - 4; }
  } else if (fb < 12){ W = einW; s = 0; nt = fb - 8; }
  else if (fb < 44){ int t = fb - 12; W = huW + (t >> 4)*8192;  int rem = t & 15; s = rem >> 2; nt = rem & 3; }
  else if (fb < 92){ int t = fb - 44; W = vuW + (t / 24)*12288; int rem = t % 24; s = rem >> 2; nt = rem & 3; }
  else             { int t = fb - 92; W = euW + (t >> 4)*8192;  int rem = t & 15; s = rem >> 2; nt = rem & 3; }
  int g4 = (l >> 4) << 2, col = nt*16 + (l & 15);
  unsigned short* dst = wp + ((size_t)fb*64 + l)*8;
#pragma unroll
  for (int j = 0; j < 8; ++j){
    int k = s*32 + ((j >> 2) << 4) + g4 + (j & 3);
    dst[j] = f2bf(W[k*64 + col]);
  }
}

__global__ __launch_bounds__(BLK)
void graph_enc_kernel(
    const float* __restrict__ tile,
    const int* __restrict__ h2v, const int* __restrict__ v2h,
    const int* __restrict__ e2v, const int* __restrict__ v2e,
    const v8s* __restrict__ wpack,
    const float* __restrict__ hinb, const float* __restrict__ hing, const float* __restrict__ hinbe,
    const float* __restrict__ vinb, const float* __restrict__ ving, const float* __restrict__ vinbe,
    const float* __restrict__ einb, const float* __restrict__ eing, const float* __restrict__ einbe,
    const float* __restrict__ hub,  const float* __restrict__ hug,  const float* __restrict__ hube,
    const float* __restrict__ vub,  const float* __restrict__ vug,  const float* __restrict__ vube,
    const float* __restrict__ eub,  const float* __restrict__ eug,  const float* __restrict__ eube,
    const float* __restrict__ roW,  const float* __restrict__ rob,
    const float* __restrict__ rog,  const float* __restrict__ robe,
    float* __restrict__ out)
{
  __shared__ __align__(16) unsigned char sm[SMBYTES];
  const int b = blockIdx.x, t = threadIdx.x, lane = t & 63, wv = t >> 6;

  // ---- Pz: zero-init every LDS byte ever read before being written:
  // all of GATA+GATB (incl. S0 overlay tails) + ACTS tail rows 145-159 ----
  {
    unsigned int* z = (unsigned int*)sm;
    for (int i = 5120 + t; i < 12288; i += BLK) z[i] = 0u;   // GATA+GATB
    for (int i = 4640 + t; i < 5120;  i += BLK) z[i] = 0u;   // ACTS rows 145-159
  }
  __syncthreads();

  // ---- P0: stage tile features (f32 plain + bf16 swizzled) ----
  const float* tsrc = tile + (size_t)b * 608;
  float* tilef = (float*)(sm + S0TILEF);
  for (int i = t; i < 608; i += BLK){
    float f = tsrc[i];
    tilef[i] = f;
    lds_bf_write(sm, S0TILEB, 64, i >> 5, i & 31, 7, f2bf(f));
  }
  __syncthreads();
  // ---- P1: vertex_raw ----
  {
    float* vrawf = (float*)(sm + S0VRAWF);
    int hr = t >> 5, c = t & 31;
    for (int v = hr; v < 54; v += 22){
      float s = 0.f; int cnt = 0;
#pragma unroll
      for (int j = 0; j < 3; ++j){ int ix = v2h[v*3+j]; if (ix >= 0){ s += tilef[ix*32 + c]; cnt++; } }
      float mval = s / (float)(cnt > 0 ? cnt : 1);
      vrawf[v*32 + c] = mval;
      lds_bf_write(sm, S0VRAWB, 64, v, c, 7, f2bf(mval));
    }
  }
  __syncthreads();
  // ---- P2: edge_raw ----
  {
    const float* vrawf = (const float*)(sm + S0VRAWF);
    int hr = t >> 5, c = t & 31;
    for (int e = hr; e < 72; e += 22){
      float s = 0.f; int cnt = 0;
#pragma unroll
      for (int j = 0; j < 2; ++j){ int ix = e2v[e*2+j]; if (ix >= 0){ s += vrawf[ix*32 + c]; cnt++; } }
      float mval = s / (float)(cnt > 0 ? cnt : 1);
      lds_bf_write(sm, S0ERAWB, 64, e, c, 7, f2bf(mval));
    }
  }
  __syncthreads();

  // ---- P3: stage-0 GEMMs (K=32) + LN -> ACTS. One tile per wave. ----
  {
    const v8s* hinP = wpack + FB_HIN*64;
    const v8s* vinP = wpack + FB_VIN*64;
    const v8s* einP = wpack + FB_EIN*64;
    if (wv < 2)       do_tile<0,true>(sm, wv*16,     lane, hinP, hinb, hing, hinbe);
    else if (wv < 6)  do_tile<1,true>(sm, (wv-2)*16, lane, vinP, vinb, ving, vinbe);
    else              do_tile<2,true>(sm, (wv-6)*16, lane, einP, einb, eing, einbe);
  }
  __syncthreads();

  // ---- 2 message-passing rounds (single ACTS buffer, in-place P5) ----
#pragma unroll
  for (int r = 0; r < 2; ++r){
    // P4: gathers (199 rows, wave-strided) read ACTS -> GATA/GATB
    for (int gid = wv; gid < 199; gid += 11){
      const int* idx; int deg, srcB, dbase, drow;
      if (gid < 19)      { idx = h2v + gid*6;        deg = 6; srcB = 19; dbase = GATA; drow = gid; }
      else if (gid < 73) { int v = gid-19;  idx = v2h + v*3; deg = 3; srcB = 0;  dbase = GATA; drow = 19+v; }
      else if (gid < 145){ int e = gid-73;  idx = e2v + e*2; deg = 2; srcB = 19; dbase = GATA; drow = 73+e; }
      else               { int v = gid-145; idx = v2e + v*3; deg = 3; srcB = 73; dbase = GATB; drow = v; }
      float s = 0.f; int cnt = 0;
      for (int j = 0; j < deg; ++j){
        int ix = idx[j];
        if (ix >= 0){ s += bf2f(lds_bf_read(sm, ACTS, 128, srcB+ix, lane, 15)); cnt++; }
      }
      float mval = s / (float)(cnt > 0 ? cnt : 1);
      lds_bf_write(sm, dbase, 128, drow, lane, 15, f2bf(mval));
    }
    __syncthreads();
    // P5: one tile per wave: reads own ACTS rows + GATA/GATB, writes own rows
    const v8s* huP = wpack + (FB_HU + r*16)*64;
    const v8s* vuP = wpack + (FB_VU + r*24)*64;
    const v8s* euP = wpack + (FB_EU + r*16)*64;
    if (wv < 2)       do_tile<0,false>(sm, wv*16,     lane, huP, hub + r*64, hug + r*64, hube + r*64);
    else if (wv < 6)  do_tile<1,false>(sm, (wv-2)*16, lane, vuP, vub + r*64, vug + r*64, vube + r*64);
    else              do_tile<2,false>(sm, (wv-6)*16, lane, euP, eub + r*64, eug + r*64, eube + r*64);
    __syncthreads();
  }

  // ---- P7: pooling (waves 0-2, read ACTS) + zero readout acc (wave 3) ----
  if (wv < 3){
    int R  = (wv == 0 ? 19 : (wv == 1 ? 54 : 72));
    int B0 = (wv == 0 ? 0  : (wv == 1 ? 19 : 73));
    float s = 0.f;
    for (int n = 0; n < R; ++n) s += bf2f(lds_bf_read(sm, ACTS, 128, B0+n, lane, 15));
    ((float*)(sm + POOLF))[wv*64 + lane] = s / (float)R;
  } else if (wv == 3){
    ((float*)(sm + RACC))[lane] = 0.f;
  }
  __syncthreads();
  // ---- P8: readout partials (waves 0-3, 48 K each) ----
  if (wv < 4){
    const float* pool = (const float*)(sm + POOLF);
    float s0 = 0.f, s1 = 0.f, s2 = 0.f, s3 = 0.f;
#pragma unroll 4
    for (int kk = 0; kk < 48; kk += 4){
      int k = wv*48 + kk;
      s0 = fmaf(pool[k+0], roW[(size_t)(k+0)*64 + lane], s0);
      s1 = fmaf(pool[k+1], roW[(size_t)(k+1)*64 + lane], s1);
      s2 = fmaf(pool[k+2], roW[(size_t)(k+2)*64 + lane], s2);
      s3 = fmaf(pool[k+3], roW[(size_t)(k+3)*64 + lane], s3);
    }
    atomicAdd((float*)(sm + RACC) + lane, (s0+s1) + (s2+s3));
  }
  __syncthreads();
  // ---- P9: readout LN (wave 0) ----
  if (wv == 0){
    float v = ((float*)(sm + RACC))[lane] + rob[lane];
    float mu = red64(v) * 0.015625f;
    float d = v - mu;
    float var = red64(d*d) * 0.015625f;
    float y = fmaf(d * rsqrtf(var + 1e-5f), rog[lane], robe[lane]);
    out[(size_t)b*64 + lane] = fmaxf(y, 0.f);
  }
}

extern "C" void kernel_launch(void* const* d_in, const int* in_sizes, int n_in,
                              void* d_out, int out_size, void* d_ws, size_t ws_size,
                              hipStream_t stream) {
  const float* tile = (const float*)d_in[0];
  const int* h2v  = (const int*)d_in[1];
  const int* v2h  = (const int*)d_in[2];
  const int* e2v  = (const int*)d_in[3];
  const int* v2e  = (const int*)d_in[4];
  const float* hinW = (const float*)d_in[5];
  const float* hinb = (const float*)d_in[6];
  const float* hing = (const float*)d_in[7];
  const float* hinbe= (const float*)d_in[8];
  const float* vinW = (const float*)d_in[9];
  const float* vinb = (const float*)d_in[10];
  const float* ving = (const float*)d_in[11];
  const float* vinbe= (const float*)d_in[12];
  const float* einW = (const float*)d_in[13];
  const float* einb = (const float*)d_in[14];
  const float* eing = (const float*)d_in[15];
  const float* einbe= (const float*)d_in[16];
  const float* huW  = (const float*)d_in[17];
  const float* hub  = (const float*)d_in[18];
  const float* hug  = (const float*)d_in[19];
  const float* hube = (const float*)d_in[20];
  const float* vuW  = (const float*)d_in[21];
  const float* vub  = (const float*)d_in[22];
  const float* vug  = (const float*)d_in[23];
  const float* vube = (const float*)d_in[24];
  const float* euW  = (const float*)d_in[25];
  const float* eub  = (const float*)d_in[26];
  const float* eug  = (const float*)d_in[27];
  const float* eube = (const float*)d_in[28];
  const float* roW  = (const float*)d_in[29];
  const float* rob  = (const float*)d_in[30];
  const float* rog  = (const float*)d_in[31];
  const float* robe = (const float*)d_in[32];
  float* out = (float*)d_out;

  unsigned short* wpack = (unsigned short*)d_ws;   // 124 KB used

  hipLaunchKernelGGL(pack_w_kernel, dim3(NFB), dim3(64), 0, stream,
      hinW, vinW, einW, huW, vuW, euW, wpack);

  int B = in_sizes[0] / 608;   // 16384
  hipLaunchKernelGGL(graph_enc_kernel, dim3(B), dim3(BLK), 0, stream,
      tile, h2v, v2h, e2v, v2e,
      (const v8s*)wpack,
      hinb, hing, hinbe,
      vinb, ving, vinbe,
      einb, eing, einbe,
      hub, hug, hube,
      vub, vug, vube,
      eub, eug, eube,
      roW, rob, rog, robe,
      out);
}

// Round 11
// 1664.373 us; speedup vs baseline: 2.1863x; 1.5892x over previous
//
#include <hip/hip_runtime.h>

// Fused per-batch graph encoder, v10 (resubmit; round 10 hit a broker
// acquisition timeout and never ran): MFMA bf16 + packed weights.
// v9 + (a) __launch_bounds__(704,8) -> <=64 VGPR -> 2 blocks/CU (m69: waves/SIMD
// halves at the 64-VGPR boundary; v9's 72 VGPR pinned us to 1 block/CU),
// (b) gathers vectorized as (row, 4-col-chunk) tasks with ds_read_b64 /
// ds_write_b64 (swizzle keeps 4 consecutive bf16 cols contiguous per 8B chunk).

#define BLK 704

typedef short v4s __attribute__((ext_vector_type(4)));
typedef short v8s __attribute__((ext_vector_type(8)));
typedef float v4f __attribute__((ext_vector_type(4)));

// byte offsets into the 49152-B shared block
#define ACTS    0              // 160 rows x 128B bf16, swz mask 15
#define GATA    20480          // 160 rows x 128B (h_from_v / v_from_h / e_from_v)
#define GATB    40960          // 64 rows x 128B (v_from_e)
#define SMBYTES 49152
// stage-0 overlays (inside GATA/GATB; free until the rounds)
#define S0TILEF (GATA + 0)     // 19x32 f32
#define S0VRAWF (GATA + 2432)  // 54x32 f32
#define S0TILEB (GATA + 9344)  // 32 rows x 64B bf16, swz mask 7
#define S0VRAWB (GATA + 11392) // 64 rows x 64B
#define S0ERAWB (GATB + 0)     // 80 rows x 64B
// post-round overlays (GATA dead by then; barrier-separated)
#define POOLF   (GATA + 0)     // 192 f32
#define RACC    (GATA + 768)   // 64 f32

// packed-W frag-block bases (1 block = 64 lanes x 8 bf16 = 1KB)
#define FB_HIN 0
#define FB_VIN 4
#define FB_EIN 8
#define FB_HU  12   // +16 per round
#define FB_VU  44   // +24 per round
#define FB_EU  92   // +16 per round
#define NFB    124

struct Acc4 { v4f c0, c1, c2, c3; };

__device__ __forceinline__ unsigned short f2bf(float f){
  unsigned u = __float_as_uint(f);
  return (unsigned short)((u + 0x7fffu + ((u >> 16) & 1u)) >> 16);
}
__device__ __forceinline__ float bf2f(unsigned short h){
  return __uint_as_float(((unsigned)h) << 16);
}

__device__ __forceinline__ float red16(float v){
  v += __shfl_xor(v, 1, 64);
  v += __shfl_xor(v, 2, 64);
  v += __shfl_xor(v, 4, 64);
  v += __shfl_xor(v, 8, 64);
  return v;
}
__device__ __forceinline__ float red64(float v){
#pragma unroll
  for (int m = 32; m >= 1; m >>= 1) v += __shfl_xor(v, m, 64);
  return v;
}

__device__ __forceinline__ int swz_off(int base, int stride, int row, int col, int m){
  return base + row*stride + ((((col >> 2) ^ (row & m)) << 3) + ((col & 3) << 1));
}
__device__ __forceinline__ unsigned short lds_bf_read(const unsigned char* sm, int base, int stride, int row, int col, int m){
  return *(const unsigned short*)(sm + swz_off(base, stride, row, col, m));
}
__device__ __forceinline__ void lds_bf_write(unsigned char* sm, int base, int stride, int row, int col, int m, unsigned short v){
  *(unsigned short*)(sm + swz_off(base, stride, row, col, m)) = v;
}

// A-fragment: lane l row=(l&15), k(j) = 32*seg + 16*(j>>2) + 4*(l>>4) + (j&3).
__device__ __forceinline__ v8s load_frag(const unsigned char* sm, int base, int stride, int row, int cb, int m){
  v4s lo = *(const v4s*)(sm + base + row*stride + (((cb    ) ^ (row & m)) << 3));
  v4s hi = *(const v4s*)(sm + base + row*stride + (((cb + 4) ^ (row & m)) << 3));
  v8s r; r[0]=lo[0]; r[1]=lo[1]; r[2]=lo[2]; r[3]=lo[3]; r[4]=hi[0]; r[5]=hi[1]; r[6]=hi[2]; r[7]=hi[3];
  return r;
}

// TYPE: 0=hex 1=vtx 2=edge. S0: stage-0 (K=32). Straight-line:
// accumulate + LN + in-place store (own rows only).
template<int TYPE, bool S0>
__device__ __forceinline__ void do_tile(unsigned char* sm,
    int roff, int lane, const v8s* __restrict__ wp,
    const float* __restrict__ bp, const float* __restrict__ gp, const float* __restrict__ bep)
{
  constexpr int NSEG = S0 ? 1 : (TYPE == 1 ? 6 : 4);
  constexpr int STR  = S0 ? 64 : 128;
  constexpr int MSK  = S0 ? 7  : 15;
  constexpr int TR0  = (TYPE==0 ? 0 : (TYPE==1 ? 19 : 73));
  constexpr int MV   = (TYPE==0 ? 19 : (TYPE==1 ? 54 : 72));
  const int m15 = lane & 15, g = lane >> 4;

  const v4f zz = {0.f, 0.f, 0.f, 0.f};
  Acc4 A; A.c0 = zz; A.c1 = zz; A.c2 = zz; A.c3 = zz;

#pragma unroll
  for (int s = 0; s < NSEG; ++s){
    int buf, rb, kb;
    if constexpr (S0){
      buf = (TYPE==0 ? S0TILEB : (TYPE==1 ? S0VRAWB : S0ERAWB)); rb = 0; kb = 0;
    } else {
      kb = s & 1;
      if (s < 2)      { buf = ACTS; rb = TR0; }
      else if (s < 4) { buf = GATA; rb = TR0; }
      else            { buf = GATB; rb = 0;   }
    }
    v8s af = load_frag(sm, buf, STR, rb + roff + m15, kb*8 + g, MSK);
    const v8s* w4 = wp + s*256 + lane;
    A.c0 = __builtin_amdgcn_mfma_f32_16x16x32_bf16(af, w4[0],   A.c0, 0, 0, 0);
    A.c1 = __builtin_amdgcn_mfma_f32_16x16x32_bf16(af, w4[64],  A.c1, 0, 0, 0);
    A.c2 = __builtin_amdgcn_mfma_f32_16x16x32_bf16(af, w4[128], A.c2, 0, 0, 0);
    A.c3 = __builtin_amdgcn_mfma_f32_16x16x32_bf16(af, w4[192], A.c3, 0, 0, 0);
    // Stop the scheduler hoisting the next seg's 4 global W-frag loads above
    // this point (round-8 spill source: 24 in-flight dwordx4 -> MAXLIVE blowup).
    __builtin_amdgcn_sched_barrier(0);
  }

  // LN + ReLU + bf16 store (C layout: col=l&15, row=4*(l>>4)+q)
  const int cl = m15, g4 = g << 2;
  const float b0 = bp[cl], b1 = bp[16+cl], b2 = bp[32+cl], b3 = bp[48+cl];
  const float gA = gp[cl], gB = gp[16+cl], gC = gp[32+cl], gD = gp[48+cl];
  const float e0 = bep[cl], e1 = bep[16+cl], e2 = bep[32+cl], e3 = bep[48+cl];
#pragma unroll
  for (int q = 0; q < 4; ++q){
    float y0 = A.c0[q] + b0, y1 = A.c1[q] + b1, y2 = A.c2[q] + b2, y3 = A.c3[q] + b3;
    float mu = red16(y0 + y1 + y2 + y3) * 0.015625f;
    float d0 = y0-mu, d1 = y1-mu, d2 = y2-mu, d3 = y3-mu;
    float var = red16(d0*d0 + d1*d1 + d2*d2 + d3*d3) * 0.015625f;
    float rs = rsqrtf(var + 1e-5f);
    int row = roff + g4 + q;
    if (row < MV){
      lds_bf_write(sm, ACTS, 128, TR0+row,  0+cl, 15, f2bf(fmaxf(fmaf(d0*rs, gA, e0), 0.f)));
      lds_bf_write(sm, ACTS, 128, TR0+row, 16+cl, 15, f2bf(fmaxf(fmaf(d1*rs, gB, e1), 0.f)));
      lds_bf_write(sm, ACTS, 128, TR0+row, 32+cl, 15, f2bf(fmaxf(fmaf(d2*rs, gC, e2), 0.f)));
      lds_bf_write(sm, ACTS, 128, TR0+row, 48+cl, 15, f2bf(fmaxf(fmaf(d3*rs, gD, e3), 0.f)));
    }
  }
}

// ---- prep kernel: pack all W (f32, K x 64) into bf16 B-fragment order ----
__global__ void pack_w_kernel(
    const float* __restrict__ hinW, const float* __restrict__ vinW,
    const float* __restrict__ einW, const float* __restrict__ huW,
    const float* __restrict__ vuW,  const float* __restrict__ euW,
    unsigned short* __restrict__ wp)
{
  int fb = blockIdx.x, l = threadIdx.x;
  const float* W; int s, nt;
  if (fb < 8){
    if (fb < 4){ W = hinW; s = 0; nt = fb; }
    else       { W = vinW; s = 0; nt = fb - 4; }
  } else if (fb < 12){ W = einW; s = 0; nt = fb - 8; }
  else if (fb < 44){ int t = fb - 12; W = huW + (t >> 4)*8192;  int rem = t & 15; s = rem >> 2; nt = rem & 3; }
  else if (fb < 92){ int t = fb - 44; W = vuW + (t / 24)*12288; int rem = t % 24; s = rem >> 2; nt = rem & 3; }
  else             { int t = fb - 92; W = euW + (t >> 4)*8192;  int rem = t & 15; s = rem >> 2; nt = rem & 3; }
  int g4 = (l >> 4) << 2, col = nt*16 + (l & 15);
  unsigned short* dst = wp + ((size_t)fb*64 + l)*8;
#pragma unroll
  for (int j = 0; j < 8; ++j){
    int k = s*32 + ((j >> 2) << 4) + g4 + (j & 3);
    dst[j] = f2bf(W[k*64 + col]);
  }
}

__global__ __launch_bounds__(BLK, 8)
void graph_enc_kernel(
    const float* __restrict__ tile,
    const int* __restrict__ h2v, const int* __restrict__ v2h,
    const int* __restrict__ e2v, const int* __restrict__ v2e,
    const v8s* __restrict__ wpack,
    const float* __restrict__ hinb, const float* __restrict__ hing, const float* __restrict__ hinbe,
    const float* __restrict__ vinb, const float* __restrict__ ving, const float* __restrict__ vinbe,
    const float* __restrict__ einb, const float* __restrict__ eing, const float* __restrict__ einbe,
    const float* __restrict__ hub,  const float* __restrict__ hug,  const float* __restrict__ hube,
    const float* __restrict__ vub,  const float* __restrict__ vug,  const float* __restrict__ vube,
    const float* __restrict__ eub,  const float* __restrict__ eug,  const float* __restrict__ eube,
    const float* __restrict__ roW,  const float* __restrict__ rob,
    const float* __restrict__ rog,  const float* __restrict__ robe,
    float* __restrict__ out)
{
  __shared__ __align__(16) unsigned char sm[SMBYTES];
  const int b = blockIdx.x, t = threadIdx.x, lane = t & 63, wv = t >> 6;

  // ---- Pz: zero-init every LDS byte ever read before being written:
  // all of GATA+GATB (incl. S0 overlay tails) + ACTS tail rows 145-159 ----
  {
    unsigned int* z = (unsigned int*)sm;
    for (int i = 5120 + t; i < 12288; i += BLK) z[i] = 0u;   // GATA+GATB
    for (int i = 4640 + t; i < 5120;  i += BLK) z[i] = 0u;   // ACTS rows 145-159
  }
  __syncthreads();

  // ---- P0: stage tile features (f32 plain + bf16 swizzled) ----
  const float* tsrc = tile + (size_t)b * 608;
  float* tilef = (float*)(sm + S0TILEF);
  for (int i = t; i < 608; i += BLK){
    float f = tsrc[i];
    tilef[i] = f;
    lds_bf_write(sm, S0TILEB, 64, i >> 5, i & 31, 7, f2bf(f));
  }
  __syncthreads();
  // ---- P1: vertex_raw ----
  {
    float* vrawf = (float*)(sm + S0VRAWF);
    int hr = t >> 5, c = t & 31;
    for (int v = hr; v < 54; v += 22){
      float s = 0.f; int cnt = 0;
#pragma unroll
      for (int j = 0; j < 3; ++j){ int ix = v2h[v*3+j]; if (ix >= 0){ s += tilef[ix*32 + c]; cnt++; } }
      float mval = s / (float)(cnt > 0 ? cnt : 1);
      vrawf[v*32 + c] = mval;
      lds_bf_write(sm, S0VRAWB, 64, v, c, 7, f2bf(mval));
    }
  }
  __syncthreads();
  // ---- P2: edge_raw ----
  {
    const float* vrawf = (const float*)(sm + S0VRAWF);
    int hr = t >> 5, c = t & 31;
    for (int e = hr; e < 72; e += 22){
      float s = 0.f; int cnt = 0;
#pragma unroll
      for (int j = 0; j < 2; ++j){ int ix = e2v[e*2+j]; if (ix >= 0){ s += vrawf[ix*32 + c]; cnt++; } }
      float mval = s / (float)(cnt > 0 ? cnt : 1);
      lds_bf_write(sm, S0ERAWB, 64, e, c, 7, f2bf(mval));
    }
  }
  __syncthreads();

  // ---- P3: stage-0 GEMMs (K=32) + LN -> ACTS. One tile per wave. ----
  {
    const v8s* hinP = wpack + FB_HIN*64;
    const v8s* vinP = wpack + FB_VIN*64;
    const v8s* einP = wpack + FB_EIN*64;
    if (wv < 2)       do_tile<0,true>(sm, wv*16,     lane, hinP, hinb, hing, hinbe);
    else if (wv < 6)  do_tile<1,true>(sm, (wv-2)*16, lane, vinP, vinb, ving, vinbe);
    else              do_tile<2,true>(sm, (wv-6)*16, lane, einP, einb, eing, einbe);
  }
  __syncthreads();

  // ---- 2 message-passing rounds (single ACTS buffer, in-place P5) ----
#pragma unroll
  for (int r = 0; r < 2; ++r){
    // P4: gathers, chunked: (row, 4-col chunk) tasks; ds_read_b64 per neighbor.
    // Swizzle keeps cols 4c..4c+3 contiguous in one 8B chunk at
    // byte offset ((c ^ (row&15))<<3).
    {
      const int ch = t & 15;      // chunk 0..15 (4 cols each)
      const int rg = t >> 4;      // row group 0..43
      for (int row = rg; row < 199; row += 44){
        const int* idx; int deg, srcB, dbase, drow;
        if (row < 19)      { idx = h2v + row*6;        deg = 6; srcB = 19; dbase = GATA; drow = row; }
        else if (row < 73) { int v = row-19;  idx = v2h + v*3; deg = 3; srcB = 0;  dbase = GATA; drow = 19+v; }
        else if (row < 145){ int e = row-73;  idx = e2v + e*2; deg = 2; srcB = 19; dbase = GATA; drow = 73+e; }
        else               { int v = row-145; idx = v2e + v*3; deg = 3; srcB = 73; dbase = GATB; drow = v; }
        float f0=0.f, f1=0.f, f2=0.f, f3=0.f; int cnt = 0;
        for (int j = 0; j < deg; ++j){
          int ix = idx[j];
          if (ix >= 0){
            int sr = srcB + ix;
            const unsigned int* p = (const unsigned int*)(sm + ACTS + sr*128 + ((ch ^ (sr & 15)) << 3));
            unsigned int u0 = p[0], u1 = p[1];
            f0 += __uint_as_float(u0 << 16);
            f1 += __uint_as_float(u0 & 0xffff0000u);
            f2 += __uint_as_float(u1 << 16);
            f3 += __uint_as_float(u1 & 0xffff0000u);
            cnt++;
          }
        }
        float inv = __builtin_amdgcn_rcpf((float)(cnt > 0 ? cnt : 1));
        f0 *= inv; f1 *= inv; f2 *= inv; f3 *= inv;
        unsigned int o0 = (unsigned)f2bf(f0) | ((unsigned)f2bf(f1) << 16);
        unsigned int o1 = (unsigned)f2bf(f2) | ((unsigned)f2bf(f3) << 16);
        unsigned int* q = (unsigned int*)(sm + dbase + drow*128 + ((ch ^ (drow & 15)) << 3));
        q[0] = o0; q[1] = o1;
      }
    }
    __syncthreads();
    // P5: one tile per wave: reads own ACTS rows + GATA/GATB, writes own rows
    const v8s* huP = wpack + (FB_HU + r*16)*64;
    const v8s* vuP = wpack + (FB_VU + r*24)*64;
    const v8s* euP = wpack + (FB_EU + r*16)*64;
    if (wv < 2)       do_tile<0,false>(sm, wv*16,     lane, huP, hub + r*64, hug + r*64, hube + r*64);
    else if (wv < 6)  do_tile<1,false>(sm, (wv-2)*16, lane, vuP, vub + r*64, vug + r*64, vube + r*64);
    else              do_tile<2,false>(sm, (wv-6)*16, lane, euP, eub + r*64, eug + r*64, eube + r*64);
    __syncthreads();
  }

  // ---- P7: pooling (waves 0-2, read ACTS) + zero readout acc (wave 3) ----
  if (wv < 3){
    int R  = (wv == 0 ? 19 : (wv == 1 ? 54 : 72));
    int B0 = (wv == 0 ? 0  : (wv == 1 ? 19 : 73));
    float s = 0.f;
    for (int n = 0; n < R; ++n) s += bf2f(lds_bf_read(sm, ACTS, 128, B0+n, lane, 15));
    ((float*)(sm + POOLF))[wv*64 + lane] = s / (float)R;
  } else if (wv == 3){
    ((float*)(sm + RACC))[lane] = 0.f;
  }
  __syncthreads();
  // ---- P8: readout partials (waves 0-3, 48 K each) ----
  if (wv < 4){
    const float* pool = (const float*)(sm + POOLF);
    float s0 = 0.f, s1 = 0.f, s2 = 0.f, s3 = 0.f;
#pragma unroll 4
    for (int kk = 0; kk < 48; kk += 4){
      int k = wv*48 + kk;
      s0 = fmaf(pool[k+0], roW[(size_t)(k+0)*64 + lane], s0);
      s1 = fmaf(pool[k+1], roW[(size_t)(k+1)*64 + lane], s1);
      s2 = fmaf(pool[k+2], roW[(size_t)(k+2)*64 + lane], s2);
      s3 = fmaf(pool[k+3], roW[(size_t)(k+3)*64 + lane], s3);
    }
    atomicAdd((float*)(sm + RACC) + lane, (s0+s1) + (s2+s3));
  }
  __syncthreads();
  // ---- P9: readout LN (wave 0) ----
  if (wv == 0){
    float v = ((float*)(sm + RACC))[lane] + rob[lane];
    float mu = red64(v) * 0.015625f;
    float d = v - mu;
    float var = red64(d*d) * 0.015625f;
    float y = fmaf(d * rsqrtf(var + 1e-5f), rog[lane], robe[lane]);
    out[(size_t)b*64 + lane] = fmaxf(y, 0.f);
  }
}

extern "C" void kernel_launch(void* const* d_in, const int* in_sizes, int n_in,
                              void* d_out, int out_size, void* d_ws, size_t ws_size,
                              hipStream_t stream) {
  const float* tile = (const float*)d_in[0];
  const int* h2v  = (const int*)d_in[1];
  const int* v2h  = (const int*)d_in[2];
  const int* e2v  = (const int*)d_in[3];
  const int* v2e  = (const int*)d_in[4];
  const float* hinW = (const float*)d_in[5];
  const float* hinb = (const float*)d_in[6];
  const float* hing = (const float*)d_in[7];
  const float* hinbe= (const float*)d_in[8];
  const float* vinW = (const float*)d_in[9];
  const float* vinb = (const float*)d_in[10];
  const float* ving = (const float*)d_in[11];
  const float* vinbe= (const float*)d_in[12];
  const float* einW = (const float*)d_in[13];
  const float* einb = (const float*)d_in[14];
  const float* eing = (const float*)d_in[15];
  const float* einbe= (const float*)d_in[16];
  const float* huW  = (const float*)d_in[17];
  const float* hub  = (const float*)d_in[18];
  const float* hug  = (const float*)d_in[19];
  const float* hube = (const float*)d_in[20];
  const float* vuW  = (const float*)d_in[21];
  const float* vub  = (const float*)d_in[22];
  const float* vug  = (const float*)d_in[23];
  const float* vube = (const float*)d_in[24];
  const float* euW  = (const float*)d_in[25];
  const float* eub  = (const float*)d_in[26];
  const float* eug  = (const float*)d_in[27];
  const float* eube = (const float*)d_in[28];
  const float* roW  = (const float*)d_in[29];
  const float* rob  = (const float*)d_in[30];
  const float* rog  = (const float*)d_in[31];
  const float* robe = (const float*)d_in[32];
  float* out = (float*)d_out;

  unsigned short* wpack = (unsigned short*)d_ws;   // 124 KB used

  hipLaunchKernelGGL(pack_w_kernel, dim3(NFB), dim3(64), 0, stream,
      hinW, vinW, einW, huW, vuW, euW, wpack);

  int B = in_sizes[0] / 608;   // 16384
  hipLaunchKernelGGL(graph_enc_kernel, dim3(B), dim3(BLK), 0, stream,
      tile, h2v, v2h, e2v, v2e,
      (const v8s*)wpack,
      hinb, hing, hinbe,
      vinb, ving, vinbe,
      einb, eing, einbe,
      hub, hug, hube,
      vub, vug, vube,
      eub, eug, eube,
      roW, rob, rog, robe,
      out);
}